// Round 1
// baseline (195.611 us; speedup 1.0000x reference)
//
#include <hip/hip_runtime.h>
#include <cstddef>

// QSelfAttention MI355X round 9: flash occupancy 2x + XCD swizzle.
// Post-mortem r8: flash counters show NOTHING busy (Mfma 15%, VALU 30%,
// HBM 14.5%, Occ 18.5%) -> latency-bound; grid (512 blocks) capped CU at
// 2 blocks. This round: c-tile 256->128 => 1024 blocks = 4 blocks/CU
// (LDS 33.8KB), bijective XCD swizzle (each XCD gets 2 whole batches,
// ~2.5MB working set < 4MB L2; FETCH was 43MB vs 20MB compulsory).
// Accepted cost: S-phase+exp2 duplicated 4x instead of 2x (idle pipes).
//   prep  : x transpose->bf16 + weight conversions
//   k1    : QK projection (TM=64, q pre-scaled by 0.125*log2e) + V (TM=128)
//   flash : q64 x c128, 16 chunks x 64 keys, Q in regs, exp2, 3 barriers
//   k4    : Wo proj + gamma*(.)+x residual epilogue (exact fp32)

typedef unsigned short ushort_t;
typedef __attribute__((ext_vector_type(8))) short bf16x8;
typedef __attribute__((ext_vector_type(4))) float f32x4;

#define QSCALE 0.18033688011112042f  // 0.125 * log2(e)

// truncating f32->bf16: 1 VALU op (intermediates only; tolerance ~2^-8 ok)
__device__ __forceinline__ ushort_t f2bf_t(float f) {
  return (ushort_t)(__float_as_uint(f) >> 16);
}
// pack 2 f32 -> 2 bf16 in one dword: single v_perm_b32
__device__ __forceinline__ unsigned pk2bf(float lo, float hi) {
  return __builtin_amdgcn_perm(__float_as_uint(hi), __float_as_uint(lo),
                               0x07060302u);
}

__device__ __forceinline__ void gload16(const ushort_t* g, ushort_t* l) {
  __builtin_amdgcn_global_load_lds(
      (const __attribute__((address_space(1))) void*)g,
      (__attribute__((address_space(3))) void*)l, 16, 0, 0);
}

// ---------------------------------------------------------------------------
// Core NT GEMM: D[M][N] = A[M][K] * B[N][K]^T, bf16 in, fp32 acc.
// TM in {64,128}, TN=128, BK=64, 256 threads (4 waves, 2x2 wave grid).
template <int TM>
__device__ __forceinline__ void gemm_core(
    const ushort_t* __restrict__ A, int lda,
    const ushort_t* __restrict__ B, int ldb,
    int K, int m0, int n0,
    ushort_t* As, ushort_t* Bs, f32x4 (*acc)[4])
{
  constexpr int MT  = TM / 32;
  constexpr int WTM = TM / 2;
  const int t = threadIdx.x;
  const int lane = t & 63, quad = lane >> 4, l15 = lane & 15;
  const int w = t >> 6, wm = w >> 1, wn = w & 1;
  const int rr = (lane >> 3) & 7;
  const int gg = (lane & 7) ^ rr;

  #pragma unroll
  for (int i = 0; i < MT; ++i)
    #pragma unroll
    for (int j = 0; j < 4; ++j) acc[i][j] = (f32x4){0.f, 0.f, 0.f, 0.f};

  for (int k0 = 0; k0 < K; k0 += 64) {
    #pragma unroll
    for (int i = 0; i < TM / 32; ++i) {
      const int mrow = w * (TM / 4) + i * 8;
      gload16(A + (size_t)(m0 + mrow + rr) * lda + k0 + gg * 8, As + mrow * 64);
    }
    #pragma unroll
    for (int i = 0; i < 4; ++i) {
      const int mrow = w * 32 + i * 8;
      gload16(B + (size_t)(n0 + mrow + rr) * ldb + k0 + gg * 8, Bs + mrow * 64);
    }
    __syncthreads();
    #pragma unroll
    for (int kk = 0; kk < 2; ++kk) {
      const int gq = kk * 4 + quad;
      const int sg = (gq ^ (l15 & 7)) * 8;
      bf16x8 af[MT], bfr[4];
      #pragma unroll
      for (int i = 0; i < MT; ++i)
        af[i] = *(const bf16x8*)(As + (wm * WTM + i * 16 + l15) * 64 + sg);
      #pragma unroll
      for (int j = 0; j < 4; ++j)
        bfr[j] = *(const bf16x8*)(Bs + (wn * 64 + j * 16 + l15) * 64 + sg);
      #pragma unroll
      for (int i = 0; i < MT; ++i)
        #pragma unroll
        for (int j = 0; j < 4; ++j)
          acc[i][j] = __builtin_amdgcn_mfma_f32_16x16x32_bf16(
              af[i], bfr[j], acc[i][j], 0, 0, 0);
    }
    __syncthreads();
  }
}

template <int TM, class F>
__device__ __forceinline__ void store_bf16(
    ushort_t* lds, ushort_t* __restrict__ out, int ldo, int m0, int n0,
    f32x4 (*acc)[4], F f)
{
  constexpr int MT = TM / 32, WTM = TM / 2, SI = TM / 16;
  const int t = threadIdx.x;
  const int lane = t & 63, quad = lane >> 4, l15 = lane & 15;
  const int w = t >> 6, wm = w >> 1, wn = w & 1;
  #pragma unroll
  for (int i = 0; i < MT; ++i)
    #pragma unroll
    for (int j = 0; j < 4; ++j)
      #pragma unroll
      for (int r = 0; r < 4; ++r) {
        const int rl = wm * WTM + i * 16 + quad * 4 + r;
        const int cl = wn * 64 + j * 16 + l15;
        lds[rl * 136 + cl] = f2bf_t(f(i, j, r, rl, cl, acc[i][j][r]));
      }
  __syncthreads();
  #pragma unroll
  for (int i = 0; i < SI; ++i) {
    const int s = i * 256 + t, m = s >> 4, g = s & 15;
    const uint4 v = *(const uint4*)(lds + m * 136 + g * 8);
    *(uint4*)(out + (size_t)(m0 + m) * ldo + n0 + g * 8) = v;
  }
}

// ---------------------------------------------------------------------------
// prep: x[b][c][n] fp32 -> xbfT[b][n][c] bf16 (64x64 tiles, blockIdx.y<8)
//       + all weight fp32->bf16 conversions (blockIdx.y==8)
__global__ __launch_bounds__(256) void prep_x(
    const float* __restrict__ x,
    const float* __restrict__ Wq, const float* __restrict__ Wk,
    const float* __restrict__ Wv, const float* __restrict__ Wo,
    ushort_t* __restrict__ xbfT, ushort_t* __restrict__ Wqk,
    ushort_t* __restrict__ Wvb, ushort_t* __restrict__ Wob)
{
  __shared__ float T[64][65];
  const int t = threadIdx.x;
  if (blockIdx.y == 8) {
    const int id = blockIdx.z * 16 + blockIdx.x;
    #pragma unroll
    for (int p = 0; p < 5; ++p) {
      const int s = p * 256 + t;
      if (s < 1152) {
        const int u = id * 1152 + s;
        const int e = u * 2;
        float f0, f1;
        if (e < 32768)       { f0 = Wq[e];         f1 = Wq[e + 1]; }
        else if (e < 65536)  { f0 = Wk[e - 32768]; f1 = Wk[e - 32767]; }
        else if (e < 327680) { f0 = Wv[e - 65536]; f1 = Wv[e - 65535]; }
        else                 { f0 = Wo[e - 327680]; f1 = Wo[e - 327679]; }
        const unsigned pk = pk2bf(f0, f1);
        if (e < 65536)       *((unsigned*)Wqk + u) = pk;
        else if (e < 327680) *((unsigned*)Wvb + (u - 32768)) = pk;
        else                 *((unsigned*)Wob + (u - 163840)) = pk;
      }
    }
    return;
  }
  const int b = blockIdx.z, c0 = blockIdx.y * 64, n0 = blockIdx.x * 64;
  const float* xb = x + ((size_t)b * 512 + c0) * 1024 + n0;
  const int nj = t & 63, ci0 = t >> 6;
  #pragma unroll
  for (int p = 0; p < 16; ++p) {
    const int ci = p * 4 + ci0;
    T[ci][nj] = xb[(size_t)ci * 1024 + nj];
  }
  __syncthreads();
  const int c2 = (t & 31) * 2, nr0 = t >> 5;
  #pragma unroll
  for (int p = 0; p < 8; ++p) {
    const int nr = p * 8 + nr0;
    *(unsigned*)&xbfT[((size_t)b * 1024 + n0 + nr) * 512 + c0 + c2] =
        pk2bf(T[c2][nr], T[c2 + 1][nr]);
  }
}

// ---------------------------------------------------------------------------
// k1 fused: blocks 0..511 -> V projection (vt2[b][c][n], TM=128);
//           blocks 512..767 -> QK projection (qkt[b][n][128], TM=64).
// Q columns (0..63) pre-scaled by QSCALE so flash uses bare exp2f.
__global__ __launch_bounds__(256) void k1_fused(
    const ushort_t* __restrict__ xbfT, const ushort_t* __restrict__ Wqk,
    const ushort_t* __restrict__ Wvb,
    const float* __restrict__ bq, const float* __restrict__ bk,
    const float* __restrict__ bv,
    ushort_t* __restrict__ qkt, ushort_t* __restrict__ vt2)
{
  __shared__ __align__(16) ushort_t lds[17408];
  const int bid = blockIdx.x;
  const int t = threadIdx.x, lane = t & 63, quad = lane >> 4, l15 = lane & 15;
  const int w = t >> 6, wm = w >> 1, wn = w & 1;
  if (bid < 512) {
    const int b = bid >> 5, my = (bid >> 3) & 3, nx = bid & 7;
    const int m0 = my * 128, n0 = nx * 128;
    f32x4 acc[4][4];
    gemm_core<128>(Wvb, 512, xbfT + (size_t)b * 524288, 512, 512, m0, n0,
                   lds, lds + 128 * 64, acc);
    float br[4][4];
    #pragma unroll
    for (int i = 0; i < 4; ++i)
      #pragma unroll
      for (int r = 0; r < 4; ++r)
        br[i][r] = bv[m0 + wm * 64 + i * 16 + quad * 4 + r];
    store_bf16<128>(lds, vt2 + (size_t)b * 524288, 1024, m0, n0, acc,
        [&](int i, int, int r, int, int, float v) { return v + br[i][r]; });
  } else {
    const int id = bid - 512, b = id >> 4, my = id & 15;
    const int m0 = my * 64;
    f32x4 acc[2][4];
    gemm_core<64>(xbfT + (size_t)b * 524288, 512, Wqk, 512, 512, m0, 0,
                  lds, lds + 64 * 64, acc);
    float bc[4], qs[4];
    #pragma unroll
    for (int j = 0; j < 4; ++j) {
      const int col = wn * 64 + j * 16 + l15;
      bc[j] = (col < 64) ? bq[col] : bk[col - 64];
      qs[j] = (col < 64) ? QSCALE : 1.0f;
    }
    store_bf16<64>(lds, qkt + (size_t)b * 131072, 128, m0, 0, acc,
        [&](int, int j, int, int, int, float v) { return (v + bc[j]) * qs[j]; });
  }
}

// ---------------------------------------------------------------------------
// flash: per block (b, 64 q-rows m0, 128 c-cols c0); 16 chunks of 64 keys.
//   Q staged once through Ps region -> registers. Per chunk: S=Q.K^T ->
//   exp2 -> Ps (LDS bf16, trunc convert) -> O += Ps.V^T. Row sums in regs;
//   normalize + store o1[b][n][c] at end.
// LDS: Ks[64][64] | Vs[128][64] | Ps[64][72] = 33792 B -> 4 blocks/CU.
// 1-D grid of 1024 blocks, bijective XCD swizzle (nwg%8==0): XCD k gets
// wids [128k,128k+128) = batches {2k,2k+1} -> ~2.5MB working set, L2-fit.
__global__ __launch_bounds__(256) void flash_attn(
    const ushort_t* __restrict__ qkt, const ushort_t* __restrict__ vt2,
    ushort_t* __restrict__ o1)
{
  __shared__ __align__(16) ushort_t buf[16896];
  __shared__ float lsum[64][2];
  ushort_t* Ks = buf;            // 4096 ush
  ushort_t* Vs = buf + 4096;     // 8192 ush
  ushort_t* Ps = buf + 12288;    // 4608 ush (stride 72); Q-stage uses 4096

  const int t = threadIdx.x;
  const int lane = t & 63, quad = lane >> 4, l15 = lane & 15;
  const int w = t >> 6, wm = w >> 1, wn = w & 1;
  const int rr = (lane >> 3) & 7, gg = (lane & 7) ^ rr;

  // XCD-aware bijective swizzle: hw linear id -> work id
  const unsigned lin = blockIdx.x;
  const unsigned wid = (lin & 7) * 128 + (lin >> 3);
  const int b  = wid >> 6;
  const int m0 = ((wid >> 2) & 15) * 64;
  const int c0 = (wid & 3) * 128;

  const ushort_t* qb = qkt + (size_t)b * 131072;   // [n][128]: q 0..63, k 64..127
  const ushort_t* vb = vt2 + (size_t)b * 524288;   // [c][1024]

  // stage Q (64x64) into Ps region, pull fragments to registers
  #pragma unroll
  for (int i = 0; i < 2; ++i) {
    const int mrow = w * 16 + i * 8;
    gload16(qb + (size_t)(m0 + mrow + rr) * 128 + gg * 8, Ps + mrow * 64);
  }
  __syncthreads();
  bf16x8 af_q[2][2];
  #pragma unroll
  for (int kk = 0; kk < 2; ++kk) {
    const int sg = ((kk * 4 + quad) ^ (l15 & 7)) * 8;
    #pragma unroll
    for (int i = 0; i < 2; ++i)
      af_q[i][kk] = *(const bf16x8*)(Ps + (wm * 32 + i * 16 + l15) * 64 + sg);
  }

  f32x4 accO[2][4];
  #pragma unroll
  for (int i = 0; i < 2; ++i)
    #pragma unroll
    for (int j = 0; j < 4; ++j) accO[i][j] = (f32x4){0.f, 0.f, 0.f, 0.f};
  float rsum[2][4] = {{0.f, 0.f, 0.f, 0.f}, {0.f, 0.f, 0.f, 0.f}};

  // hoisted Ps write base: row base (wm*32 + quad*4), col base wn*32 + l15
  ushort_t* ps_w = Ps + (wm * 32 + quad * 4) * 72 + wn * 32 + l15;

  #pragma unroll 1
  for (int mc = 0; mc < 1024; mc += 64) {
    __syncthreads();  // A: prev chunk's LDS reads (and Q-frag reads) complete
    #pragma unroll
    for (int i = 0; i < 2; ++i) {
      const int mrow = w * 16 + i * 8;
      gload16(qb + (size_t)(mc + mrow + rr) * 128 + 64 + gg * 8, Ks + mrow * 64);
    }
    #pragma unroll
    for (int i = 0; i < 4; ++i) {
      const int mrow = w * 32 + i * 8;
      gload16(vb + (size_t)(c0 + mrow + rr) * 1024 + mc + gg * 8, Vs + mrow * 64);
    }
    __syncthreads();  // B: DMA drained

    // S-phase: rows wm*32+{0,16}, keys wn*32+{0,16}, K=64 (Q pre-scaled)
    f32x4 accS[2][2];
    #pragma unroll
    for (int i = 0; i < 2; ++i)
      #pragma unroll
      for (int j = 0; j < 2; ++j) accS[i][j] = (f32x4){0.f, 0.f, 0.f, 0.f};
    #pragma unroll
    for (int kk = 0; kk < 2; ++kk) {
      const int sg = ((kk * 4 + quad) ^ (l15 & 7)) * 8;
      bf16x8 bk_[2];
      #pragma unroll
      for (int j = 0; j < 2; ++j)
        bk_[j] = *(const bf16x8*)(Ks + (wn * 32 + j * 16 + l15) * 64 + sg);
      #pragma unroll
      for (int i = 0; i < 2; ++i)
        #pragma unroll
        for (int j = 0; j < 2; ++j)
          accS[i][j] = __builtin_amdgcn_mfma_f32_16x16x32_bf16(
              af_q[i][kk], bk_[j], accS[i][j], 0, 0, 0);
    }
    // exp2 (scale folded into Q) -> rsum partials -> Ps (trunc convert, 1 op)
    #pragma unroll
    for (int i = 0; i < 2; ++i)
      #pragma unroll
      for (int j = 0; j < 2; ++j)
        #pragma unroll
        for (int r = 0; r < 4; ++r) {
          const float e = exp2f(accS[i][j][r]);
          rsum[i][r] += e;
          ps_w[(i * 16 + r) * 72 + j * 16] = f2bf_t(e);
        }
    __syncthreads();  // C: Ps visible

    // PV-phase: O[64][128] += Ps[64][64] . Vs[128][64]^T
    #pragma unroll
    for (int kk = 0; kk < 2; ++kk) {
      const int gq = kk * 4 + quad;
      const int sgv = (gq ^ (l15 & 7)) * 8;
      bf16x8 ap[2], bv_[4];
      #pragma unroll
      for (int i = 0; i < 2; ++i)
        ap[i] = *(const bf16x8*)(Ps + (wm * 32 + i * 16 + l15) * 72 + gq * 8);
      #pragma unroll
      for (int j = 0; j < 4; ++j)
        bv_[j] = *(const bf16x8*)(Vs + (wn * 64 + j * 16 + l15) * 64 + sgv);
      #pragma unroll
      for (int i = 0; i < 2; ++i)
        #pragma unroll
        for (int j = 0; j < 4; ++j)
          accO[i][j] = __builtin_amdgcn_mfma_f32_16x16x32_bf16(
              ap[i], bv_[j], accO[i][j], 0, 0, 0);
    }
  }

  // finish row sums: reduce over the 16 key-lanes, combine the two wn waves
  #pragma unroll
  for (int i = 0; i < 2; ++i)
    #pragma unroll
    for (int r = 0; r < 4; ++r) {
      float s = rsum[i][r];
      #pragma unroll
      for (int d = 1; d < 16; d <<= 1) s += __shfl_xor(s, d, 16);
      if (l15 == 0) lsum[wm * 32 + i * 16 + quad * 4 + r][wn] = s;
    }
  __syncthreads();  // also: last PV's LDS reads done before fl_b overwrite

  ushort_t* fl_b = buf;  // [64][136] = 8704 ush, fits (Ks/Vs/Ps dead)
  #pragma unroll
  for (int i = 0; i < 2; ++i)
    #pragma unroll
    for (int r = 0; r < 4; ++r) {
      const int row = wm * 32 + i * 16 + quad * 4 + r;
      const float inv = 1.0f / (lsum[row][0] + lsum[row][1]);
      #pragma unroll
      for (int j = 0; j < 4; ++j)
        fl_b[row * 136 + wn * 64 + j * 16 + l15] = f2bf_t(accO[i][j][r] * inv);
    }
  __syncthreads();
  #pragma unroll
  for (int p = 0; p < 4; ++p) {
    const int s = p * 256 + t, m = s >> 4, g = s & 15;
    const uint4 v = *(const uint4*)(fl_b + m * 136 + g * 8);
    *(uint4*)(o1 + ((size_t)b * 1024 + m0 + m) * 512 + c0 + g * 8) = v;
  }
}

// ---------------------------------------------------------------------------
// K4: out[b][c][n] = g*(Wo @ o1^T + bo) + x.  M=c(512) N=n(1024) K=v(512)
// Residual path kept exact fp32.
__global__ __launch_bounds__(256) void k4_proj(
    const ushort_t* __restrict__ Wob, const ushort_t* __restrict__ o1,
    const float* __restrict__ bo, const float* __restrict__ gamma,
    const float* __restrict__ x, float* __restrict__ out)
{
  __shared__ __align__(16) ushort_t lds[128 * 136];
  const int b = blockIdx.z, m0 = blockIdx.y * 128, n0 = blockIdx.x * 128;
  f32x4 acc[4][4];
  gemm_core<128>(Wob, 512, o1 + (size_t)b * 524288, 512, 512, m0, n0,
                 lds, lds + 128 * 64, acc);
  const int t = threadIdx.x, lane = t & 63, quad = lane >> 4, l15 = lane & 15;
  const int w = t >> 6, wm = w >> 1, wn = w & 1;
  const float g = gamma[0];
  float br[4][4];
  #pragma unroll
  for (int i = 0; i < 4; ++i)
    #pragma unroll
    for (int r = 0; r < 4; ++r)
      br[i][r] = bo[m0 + wm * 64 + i * 16 + quad * 4 + r];
  float* fl = (float*)lds;  // 64 rows x 132 f stride
  #pragma unroll
  for (int h = 0; h < 2; ++h) {
    if (wm == h) {
      #pragma unroll
      for (int i = 0; i < 4; ++i)
        #pragma unroll
        for (int j = 0; j < 4; ++j)
          #pragma unroll
          for (int r = 0; r < 4; ++r)
            fl[(i * 16 + quad * 4 + r) * 132 + wn * 64 + j * 16 + l15] =
                g * (acc[i][j][r] + br[i][r]);
    }
    __syncthreads();
    #pragma unroll
    for (int i2 = 0; i2 < 8; ++i2) {
      const int s = i2 * 256 + t, m = s >> 5, c4 = s & 31;
      f32x4 v = *(const f32x4*)(fl + m * 132 + c4 * 4);
      const size_t gi = ((size_t)b * 512 + m0 + h * 64 + m) * 1024 + n0 + c4 * 4;
      const f32x4 xr = *(const f32x4*)(x + gi);
      v += xr;
      *(f32x4*)(out + gi) = v;
    }
    __syncthreads();
  }
}

// ---------------------------------------------------------------------------
extern "C" void kernel_launch(void* const* d_in, const int* in_sizes, int n_in,
                              void* d_out, int out_size, void* d_ws, size_t ws_size,
                              hipStream_t stream) {
  const float* x     = (const float*)d_in[0];
  const float* Wq    = (const float*)d_in[1];
  const float* bq    = (const float*)d_in[2];
  const float* Wk    = (const float*)d_in[3];
  const float* bk    = (const float*)d_in[4];
  const float* Wv    = (const float*)d_in[5];
  const float* bv    = (const float*)d_in[6];
  const float* Wo    = (const float*)d_in[7];
  const float* bo    = (const float*)d_in[8];
  const float* gamma = (const float*)d_in[9];
  float* out = (float*)d_out;

  char* wsp = (char*)d_ws;
  ushort_t* xbfT   = (ushort_t*)wsp;  wsp += (size_t)16 * 1024 * 512 * 2;  // 16 MB
  ushort_t* Wqk_bf = (ushort_t*)wsp;  wsp += (size_t)128 * 512 * 2;
  ushort_t* Wv_bf  = (ushort_t*)wsp;  wsp += (size_t)512 * 512 * 2;
  ushort_t* Wo_bf  = (ushort_t*)wsp;  wsp += (size_t)512 * 512 * 2;
  ushort_t* qkt    = (ushort_t*)wsp;  wsp += (size_t)16 * 1024 * 128 * 2;  // 4 MB
  ushort_t* vt2    = (ushort_t*)wsp;  wsp += (size_t)16 * 512 * 1024 * 2;  // 16 MB
  ushort_t* o1     = xbfT;  // xbfT dead after k1; reuse for o1

  prep_x    <<<dim3(16, 9, 16), 256, 0, stream>>>(x, Wq, Wk, Wv, Wo,
                                                  xbfT, Wqk_bf, Wv_bf, Wo_bf);
  k1_fused  <<<768, 256, 0, stream>>>(xbfT, Wqk_bf, Wv_bf, bq, bk, bv, qkt, vt2);
  flash_attn<<<dim3(1024), 256, 0, stream>>>(qkt, vt2, o1);
  k4_proj   <<<dim3(8, 4, 16), 256, 0, stream>>>(Wo_bf, o1, bo, gamma, x, out);
}

// Round 2
// 188.886 us; speedup vs baseline: 1.0356x; 1.0356x over previous
//
#include <hip/hip_runtime.h>
#include <cstddef>

// QSelfAttention MI355X round 10: flash 2-phase pipeline (hide DMA drain).
// Post-mortem r9: c-tile halving was a regression (52.5->59.3us): all blocks
// are co-resident either way, so duration = per-block critical path; halving
// the tile doubled S+exp2 work (VALUBusy 30->45%) without shortening the
// chain. The chain is 16 serial chunks x (DMA issue -> vmcnt(0) drain ->
// S -> barrier -> PV -> barrier) ~= 8900 cyc/chunk vs ~1500 compute.
// This round: double-buffer Ks/Vs/Ps, prefetch next chunk BEFORE computing
// current, raw s_barrier + explicit counted waits (catalog T3-min/T4) so the
// prefetch stays in flight across the Ps barrier. 2 barriers/chunk, DMA off
// the critical path. exp2f -> __builtin_amdgcn_exp2f (1 op, no ocml fixup).
// XCD swizzle kept (FETCH 43->10MB proven in r9).
//   prep  : x transpose->bf16 + weight conversions
//   k1    : QK projection (TM=64, q pre-scaled by 0.125*log2e) + V (TM=128)
//   flash : q64 x c128, 16 chunks x 64 keys, dbuf pipeline, 2 barriers/chunk
//   k4    : Wo proj + gamma*(.)+x residual epilogue (exact fp32)

typedef unsigned short ushort_t;
typedef __attribute__((ext_vector_type(8))) short bf16x8;
typedef __attribute__((ext_vector_type(4))) float f32x4;

#define QSCALE 0.18033688011112042f  // 0.125 * log2(e)

// truncating f32->bf16: 1 VALU op (intermediates only; tolerance ~2^-8 ok)
__device__ __forceinline__ ushort_t f2bf_t(float f) {
  return (ushort_t)(__float_as_uint(f) >> 16);
}
// pack 2 f32 -> 2 bf16 in one dword: single v_perm_b32
__device__ __forceinline__ unsigned pk2bf(float lo, float hi) {
  return __builtin_amdgcn_perm(__float_as_uint(hi), __float_as_uint(lo),
                               0x07060302u);
}

__device__ __forceinline__ void gload16(const ushort_t* g, ushort_t* l) {
  __builtin_amdgcn_global_load_lds(
      (const __attribute__((address_space(1))) void*)g,
      (__attribute__((address_space(3))) void*)l, 16, 0, 0);
}

// ---------------------------------------------------------------------------
// Core NT GEMM: D[M][N] = A[M][K] * B[N][K]^T, bf16 in, fp32 acc.
// TM in {64,128}, TN=128, BK=64, 256 threads (4 waves, 2x2 wave grid).
template <int TM>
__device__ __forceinline__ void gemm_core(
    const ushort_t* __restrict__ A, int lda,
    const ushort_t* __restrict__ B, int ldb,
    int K, int m0, int n0,
    ushort_t* As, ushort_t* Bs, f32x4 (*acc)[4])
{
  constexpr int MT  = TM / 32;
  constexpr int WTM = TM / 2;
  const int t = threadIdx.x;
  const int lane = t & 63, quad = lane >> 4, l15 = lane & 15;
  const int w = t >> 6, wm = w >> 1, wn = w & 1;
  const int rr = (lane >> 3) & 7;
  const int gg = (lane & 7) ^ rr;

  #pragma unroll
  for (int i = 0; i < MT; ++i)
    #pragma unroll
    for (int j = 0; j < 4; ++j) acc[i][j] = (f32x4){0.f, 0.f, 0.f, 0.f};

  for (int k0 = 0; k0 < K; k0 += 64) {
    #pragma unroll
    for (int i = 0; i < TM / 32; ++i) {
      const int mrow = w * (TM / 4) + i * 8;
      gload16(A + (size_t)(m0 + mrow + rr) * lda + k0 + gg * 8, As + mrow * 64);
    }
    #pragma unroll
    for (int i = 0; i < 4; ++i) {
      const int mrow = w * 32 + i * 8;
      gload16(B + (size_t)(n0 + mrow + rr) * ldb + k0 + gg * 8, Bs + mrow * 64);
    }
    __syncthreads();
    #pragma unroll
    for (int kk = 0; kk < 2; ++kk) {
      const int gq = kk * 4 + quad;
      const int sg = (gq ^ (l15 & 7)) * 8;
      bf16x8 af[MT], bfr[4];
      #pragma unroll
      for (int i = 0; i < MT; ++i)
        af[i] = *(const bf16x8*)(As + (wm * WTM + i * 16 + l15) * 64 + sg);
      #pragma unroll
      for (int j = 0; j < 4; ++j)
        bfr[j] = *(const bf16x8*)(Bs + (wn * 64 + j * 16 + l15) * 64 + sg);
      #pragma unroll
      for (int i = 0; i < MT; ++i)
        #pragma unroll
        for (int j = 0; j < 4; ++j)
          acc[i][j] = __builtin_amdgcn_mfma_f32_16x16x32_bf16(
              af[i], bfr[j], acc[i][j], 0, 0, 0);
    }
    __syncthreads();
  }
}

template <int TM, class F>
__device__ __forceinline__ void store_bf16(
    ushort_t* lds, ushort_t* __restrict__ out, int ldo, int m0, int n0,
    f32x4 (*acc)[4], F f)
{
  constexpr int MT = TM / 32, WTM = TM / 2, SI = TM / 16;
  const int t = threadIdx.x;
  const int lane = t & 63, quad = lane >> 4, l15 = lane & 15;
  const int w = t >> 6, wm = w >> 1, wn = w & 1;
  #pragma unroll
  for (int i = 0; i < MT; ++i)
    #pragma unroll
    for (int j = 0; j < 4; ++j)
      #pragma unroll
      for (int r = 0; r < 4; ++r) {
        const int rl = wm * WTM + i * 16 + quad * 4 + r;
        const int cl = wn * 64 + j * 16 + l15;
        lds[rl * 136 + cl] = f2bf_t(f(i, j, r, rl, cl, acc[i][j][r]));
      }
  __syncthreads();
  #pragma unroll
  for (int i = 0; i < SI; ++i) {
    const int s = i * 256 + t, m = s >> 4, g = s & 15;
    const uint4 v = *(const uint4*)(lds + m * 136 + g * 8);
    *(uint4*)(out + (size_t)(m0 + m) * ldo + n0 + g * 8) = v;
  }
}

// ---------------------------------------------------------------------------
// prep: x[b][c][n] fp32 -> xbfT[b][n][c] bf16 (64x64 tiles, blockIdx.y<8)
//       + all weight fp32->bf16 conversions (blockIdx.y==8)
__global__ __launch_bounds__(256) void prep_x(
    const float* __restrict__ x,
    const float* __restrict__ Wq, const float* __restrict__ Wk,
    const float* __restrict__ Wv, const float* __restrict__ Wo,
    ushort_t* __restrict__ xbfT, ushort_t* __restrict__ Wqk,
    ushort_t* __restrict__ Wvb, ushort_t* __restrict__ Wob)
{
  __shared__ float T[64][65];
  const int t = threadIdx.x;
  if (blockIdx.y == 8) {
    const int id = blockIdx.z * 16 + blockIdx.x;
    #pragma unroll
    for (int p = 0; p < 5; ++p) {
      const int s = p * 256 + t;
      if (s < 1152) {
        const int u = id * 1152 + s;
        const int e = u * 2;
        float f0, f1;
        if (e < 32768)       { f0 = Wq[e];         f1 = Wq[e + 1]; }
        else if (e < 65536)  { f0 = Wk[e - 32768]; f1 = Wk[e - 32767]; }
        else if (e < 327680) { f0 = Wv[e - 65536]; f1 = Wv[e - 65535]; }
        else                 { f0 = Wo[e - 327680]; f1 = Wo[e - 327679]; }
        const unsigned pk = pk2bf(f0, f1);
        if (e < 65536)       *((unsigned*)Wqk + u) = pk;
        else if (e < 327680) *((unsigned*)Wvb + (u - 32768)) = pk;
        else                 *((unsigned*)Wob + (u - 163840)) = pk;
      }
    }
    return;
  }
  const int b = blockIdx.z, c0 = blockIdx.y * 64, n0 = blockIdx.x * 64;
  const float* xb = x + ((size_t)b * 512 + c0) * 1024 + n0;
  const int nj = t & 63, ci0 = t >> 6;
  #pragma unroll
  for (int p = 0; p < 16; ++p) {
    const int ci = p * 4 + ci0;
    T[ci][nj] = xb[(size_t)ci * 1024 + nj];
  }
  __syncthreads();
  const int c2 = (t & 31) * 2, nr0 = t >> 5;
  #pragma unroll
  for (int p = 0; p < 8; ++p) {
    const int nr = p * 8 + nr0;
    *(unsigned*)&xbfT[((size_t)b * 1024 + n0 + nr) * 512 + c0 + c2] =
        pk2bf(T[c2][nr], T[c2 + 1][nr]);
  }
}

// ---------------------------------------------------------------------------
// k1 fused: blocks 0..511 -> V projection (vt2[b][c][n], TM=128);
//           blocks 512..767 -> QK projection (qkt[b][n][128], TM=64).
// Q columns (0..63) pre-scaled by QSCALE so flash uses bare exp2.
__global__ __launch_bounds__(256) void k1_fused(
    const ushort_t* __restrict__ xbfT, const ushort_t* __restrict__ Wqk,
    const ushort_t* __restrict__ Wvb,
    const float* __restrict__ bq, const float* __restrict__ bk,
    const float* __restrict__ bv,
    ushort_t* __restrict__ qkt, ushort_t* __restrict__ vt2)
{
  __shared__ __align__(16) ushort_t lds[17408];
  const int bid = blockIdx.x;
  const int t = threadIdx.x, lane = t & 63, quad = lane >> 4, l15 = lane & 15;
  const int w = t >> 6, wm = w >> 1, wn = w & 1;
  if (bid < 512) {
    const int b = bid >> 5, my = (bid >> 3) & 3, nx = bid & 7;
    const int m0 = my * 128, n0 = nx * 128;
    f32x4 acc[4][4];
    gemm_core<128>(Wvb, 512, xbfT + (size_t)b * 524288, 512, 512, m0, n0,
                   lds, lds + 128 * 64, acc);
    float br[4][4];
    #pragma unroll
    for (int i = 0; i < 4; ++i)
      #pragma unroll
      for (int r = 0; r < 4; ++r)
        br[i][r] = bv[m0 + wm * 64 + i * 16 + quad * 4 + r];
    store_bf16<128>(lds, vt2 + (size_t)b * 524288, 1024, m0, n0, acc,
        [&](int i, int, int r, int, int, float v) { return v + br[i][r]; });
  } else {
    const int id = bid - 512, b = id >> 4, my = id & 15;
    const int m0 = my * 64;
    f32x4 acc[2][4];
    gemm_core<64>(xbfT + (size_t)b * 524288, 512, Wqk, 512, 512, m0, 0,
                  lds, lds + 64 * 64, acc);
    float bc[4], qs[4];
    #pragma unroll
    for (int j = 0; j < 4; ++j) {
      const int col = wn * 64 + j * 16 + l15;
      bc[j] = (col < 64) ? bq[col] : bk[col - 64];
      qs[j] = (col < 64) ? QSCALE : 1.0f;
    }
    store_bf16<64>(lds, qkt + (size_t)b * 131072, 128, m0, 0, acc,
        [&](int, int j, int, int, int, float v) { return (v + bc[j]) * qs[j]; });
  }
}

// ---------------------------------------------------------------------------
// flash: per block (b, 64 q-rows m0, 128 c-cols c0); 16 chunks of 64 keys.
// Double-buffered 2-phase pipeline:
//   prologue: stage Q -> regs; stage chunk0 -> buf0; wait+barrier
//   per chunk p: STAGE(next -> buf[p^1]) ; S=Q.K^T from Ks[p] ; exp2 ->
//     Ps[p] ; lgkmcnt(0)+s_barrier ; PV += Ps[p].Vs[p]^T ; vmcnt(0)+s_barrier
// Raw s_barrier + explicit waits: prefetch stays in flight across the Ps
// barrier (T4); DMA drain overlapped by S+exp2+PV.
// LDS (ush): Ks0 0 | Ks1 4096 | Vs0 8192 | Vs1 16384 | Ps0 24576 | Ps1 29184
//   total 33792 ush = 67.6 KB (+lsum) -> 2 blocks/CU.
// 1024 blocks, bijective XCD swizzle (nwg%8==0): XCD k gets 2 whole batches
// (~2.5MB working set, L2-fit; r9 measured FETCH 43->10MB).
__global__ __launch_bounds__(256) void flash_attn(
    const ushort_t* __restrict__ qkt, const ushort_t* __restrict__ vt2,
    ushort_t* __restrict__ o1)
{
  __shared__ __align__(16) ushort_t buf[33792];
  __shared__ float lsum[64][2];
  ushort_t* Ks0 = buf;            // 2 x 4096 ush
  ushort_t* Vs0 = buf + 8192;     // 2 x 8192 ush
  ushort_t* Ps0 = buf + 24576;    // 2 x 4608 ush (stride 72); Q-stage uses Ps0

  const int t = threadIdx.x;
  const int lane = t & 63, quad = lane >> 4, l15 = lane & 15;
  const int w = t >> 6, wm = w >> 1, wn = w & 1;
  const int rr = (lane >> 3) & 7, gg = (lane & 7) ^ rr;

  // XCD-aware bijective swizzle: hw linear id -> work id
  const unsigned lin = blockIdx.x;
  const unsigned wid = (lin & 7) * 128 + (lin >> 3);
  const int b  = wid >> 6;
  const int m0 = ((wid >> 2) & 15) * 64;
  const int c0 = (wid & 3) * 128;

  const ushort_t* qb = qkt + (size_t)b * 131072;   // [n][128]: q 0..63, k 64..127
  const ushort_t* vb = vt2 + (size_t)b * 524288;   // [c][1024]

  // ---- prologue: stage Q (64x64) into Ps0 region
  #pragma unroll
  for (int i = 0; i < 2; ++i) {
    const int mrow = w * 16 + i * 8;
    gload16(qb + (size_t)(m0 + mrow + rr) * 128 + gg * 8, Ps0 + mrow * 64);
  }
  asm volatile("s_waitcnt vmcnt(0)" ::: "memory");
  __builtin_amdgcn_s_barrier();

  // pull Q fragments to registers
  bf16x8 af_q[2][2];
  #pragma unroll
  for (int kk = 0; kk < 2; ++kk) {
    const int sg = ((kk * 4 + quad) ^ (l15 & 7)) * 8;
    #pragma unroll
    for (int i = 0; i < 2; ++i)
      af_q[i][kk] = *(const bf16x8*)(Ps0 + (wm * 32 + i * 16 + l15) * 64 + sg);
  }

  // running global source pointers (advance per chunk)
  const ushort_t* kp = qb + (size_t)(w * 16 + rr) * 128 + 64 + gg * 8;
  const ushort_t* vp = vb + (size_t)(c0 + w * 32 + rr) * 1024 + gg * 8;

  // stage chunk 0 into buf0
  #pragma unroll
  for (int i = 0; i < 2; ++i)
    gload16(kp + i * 1024, Ks0 + (w * 16 + i * 8) * 64);
  #pragma unroll
  for (int i = 0; i < 4; ++i)
    gload16(vp + i * 8192, Vs0 + (w * 32 + i * 8) * 64);
  // own Q-frag ds_reads done (lgkm) + chunk0 DMA landed (vm); then barrier:
  // all waves' Q reads done -> Ps0 writable; chunk0 visible.
  asm volatile("s_waitcnt vmcnt(0) lgkmcnt(0)" ::: "memory");
  __builtin_amdgcn_s_barrier();

  f32x4 accO[2][4];
  #pragma unroll
  for (int i = 0; i < 2; ++i)
    #pragma unroll
    for (int j = 0; j < 4; ++j) accO[i][j] = (f32x4){0.f, 0.f, 0.f, 0.f};
  float rsum[2][4] = {{0.f, 0.f, 0.f, 0.f}, {0.f, 0.f, 0.f, 0.f}};

  // hoisted per-lane invariants
  const int psw_off = (wm * 32 + quad * 4) * 72 + wn * 32 + l15;
  const int sg0 = (quad ^ (l15 & 7)) * 8;
  const int sg1 = ((4 + quad) ^ (l15 & 7)) * 8;

  const ushort_t* kpn = kp + 8192;  // next-chunk K source
  const ushort_t* vpn = vp + 64;    // next-chunk V source
  int p = 0;

  #pragma unroll 1
  for (int mc = 0; mc < 1024; mc += 64) {
    ushort_t* Ksd = p ? Ks0 + 4096 : Ks0;
    ushort_t* Vsd = p ? Vs0 + 8192 : Vs0;
    ushort_t* Psd = p ? Ps0 + 4608 : Ps0;
    ushort_t* Ksn = p ? Ks0 : Ks0 + 4096;
    ushort_t* Vsn = p ? Vs0 : Vs0 + 8192;

    // 1) prefetch next chunk into the other buffer (stays in flight)
    if (mc < 960) {
      #pragma unroll
      for (int i = 0; i < 2; ++i)
        gload16(kpn + i * 1024, Ksn + (w * 16 + i * 8) * 64);
      #pragma unroll
      for (int i = 0; i < 4; ++i)
        gload16(vpn + i * 8192, Vsn + (w * 32 + i * 8) * 64);
    }

    // 2) S-phase: rows wm*32+{0,16}, keys wn*32+{0,16}, K=64 (Q pre-scaled)
    f32x4 accS[2][2];
    #pragma unroll
    for (int i = 0; i < 2; ++i)
      #pragma unroll
      for (int j = 0; j < 2; ++j) accS[i][j] = (f32x4){0.f, 0.f, 0.f, 0.f};
    #pragma unroll
    for (int kk = 0; kk < 2; ++kk) {
      const int sg = kk ? sg1 : sg0;
      bf16x8 bk_[2];
      #pragma unroll
      for (int j = 0; j < 2; ++j)
        bk_[j] = *(const bf16x8*)(Ksd + (wn * 32 + j * 16 + l15) * 64 + sg);
      #pragma unroll
      for (int i = 0; i < 2; ++i)
        #pragma unroll
        for (int j = 0; j < 2; ++j)
          accS[i][j] = __builtin_amdgcn_mfma_f32_16x16x32_bf16(
              af_q[i][kk], bk_[j], accS[i][j], 0, 0, 0);
    }

    // 3) exp2 -> rsum partials -> Ps[p] (trunc bf16)
    ushort_t* psw = Psd + psw_off;
    #pragma unroll
    for (int i = 0; i < 2; ++i)
      #pragma unroll
      for (int j = 0; j < 2; ++j)
        #pragma unroll
        for (int r = 0; r < 4; ++r) {
          const float e = __builtin_amdgcn_exp2f(accS[i][j][r]);
          rsum[i][r] += e;
          psw[(i * 16 + r) * 72 + j * 16] = f2bf_t(e);
        }

    // 4) own ds ops done -> barrier: Ps[p] visible (prefetch NOT drained)
    asm volatile("s_waitcnt lgkmcnt(0)" ::: "memory");
    __builtin_amdgcn_s_barrier();

    // 5) PV-phase: O[64][128] += Ps[p][64][64] . Vs[p][128][64]^T
    #pragma unroll
    for (int kk = 0; kk < 2; ++kk) {
      const int gq = kk * 4 + quad;
      const int sgv = kk ? sg1 : sg0;
      bf16x8 ap[2], bv_[4];
      #pragma unroll
      for (int i = 0; i < 2; ++i)
        ap[i] = *(const bf16x8*)(Psd + (wm * 32 + i * 16 + l15) * 72 + gq * 8);
      #pragma unroll
      for (int j = 0; j < 4; ++j)
        bv_[j] = *(const bf16x8*)(Vsd + (wn * 64 + j * 16 + l15) * 64 + sgv);
      #pragma unroll
      for (int i = 0; i < 2; ++i)
        #pragma unroll
        for (int j = 0; j < 4; ++j)
          accO[i][j] = __builtin_amdgcn_mfma_f32_16x16x32_bf16(
              ap[i], bv_[j], accO[i][j], 0, 0, 0);
    }

    // 6) next chunk's DMA landed; all waves synced -> buffers swappable
    asm volatile("s_waitcnt vmcnt(0)" ::: "memory");
    __builtin_amdgcn_s_barrier();

    kpn += 8192;
    vpn += 64;
    p ^= 1;
  }

  // finish row sums: reduce over the 16 key-lanes, combine the two wn waves
  #pragma unroll
  for (int i = 0; i < 2; ++i)
    #pragma unroll
    for (int r = 0; r < 4; ++r) {
      float s = rsum[i][r];
      #pragma unroll
      for (int d = 1; d < 16; d <<= 1) s += __shfl_xor(s, d, 16);
      if (l15 == 0) lsum[wm * 32 + i * 16 + quad * 4 + r][wn] = s;
    }
  __syncthreads();  // also: last PV's LDS reads done before fl_b overwrite

  ushort_t* fl_b = buf;  // [64][136] = 8704 ush, fits (Ks/Vs/Ps dead)
  #pragma unroll
  for (int i = 0; i < 2; ++i)
    #pragma unroll
    for (int r = 0; r < 4; ++r) {
      const int row = wm * 32 + i * 16 + quad * 4 + r;
      const float inv = 1.0f / (lsum[row][0] + lsum[row][1]);
      #pragma unroll
      for (int j = 0; j < 4; ++j)
        fl_b[row * 136 + wn * 64 + j * 16 + l15] = f2bf_t(accO[i][j][r] * inv);
    }
  __syncthreads();
  #pragma unroll
  for (int pp = 0; pp < 4; ++pp) {
    const int s = pp * 256 + t, m = s >> 4, g = s & 15;
    const uint4 v = *(const uint4*)(fl_b + m * 136 + g * 8);
    *(uint4*)(o1 + ((size_t)b * 1024 + m0 + m) * 512 + c0 + g * 8) = v;
  }
}

// ---------------------------------------------------------------------------
// K4: out[b][c][n] = g*(Wo @ o1^T + bo) + x.  M=c(512) N=n(1024) K=v(512)
// Residual path kept exact fp32.
__global__ __launch_bounds__(256) void k4_proj(
    const ushort_t* __restrict__ Wob, const ushort_t* __restrict__ o1,
    const float* __restrict__ bo, const float* __restrict__ gamma,
    const float* __restrict__ x, float* __restrict__ out)
{
  __shared__ __align__(16) ushort_t lds[128 * 136];
  const int b = blockIdx.z, m0 = blockIdx.y * 128, n0 = blockIdx.x * 128;
  f32x4 acc[4][4];
  gemm_core<128>(Wob, 512, o1 + (size_t)b * 524288, 512, 512, m0, n0,
                 lds, lds + 128 * 64, acc);
  const int t = threadIdx.x, lane = t & 63, quad = lane >> 4, l15 = lane & 15;
  const int w = t >> 6, wm = w >> 1, wn = w & 1;
  const float g = gamma[0];
  float br[4][4];
  #pragma unroll
  for (int i = 0; i < 4; ++i)
    #pragma unroll
    for (int r = 0; r < 4; ++r)
      br[i][r] = bo[m0 + wm * 64 + i * 16 + quad * 4 + r];
  float* fl = (float*)lds;  // 64 rows x 132 f stride
  #pragma unroll
  for (int h = 0; h < 2; ++h) {
    if (wm == h) {
      #pragma unroll
      for (int i = 0; i < 4; ++i)
        #pragma unroll
        for (int j = 0; j < 4; ++j)
          #pragma unroll
          for (int r = 0; r < 4; ++r)
            fl[(i * 16 + quad * 4 + r) * 132 + wn * 64 + j * 16 + l15] =
                g * (acc[i][j][r] + br[i][r]);
    }
    __syncthreads();
    #pragma unroll
    for (int i2 = 0; i2 < 8; ++i2) {
      const int s = i2 * 256 + t, m = s >> 5, c4 = s & 31;
      f32x4 v = *(const f32x4*)(fl + m * 132 + c4 * 4);
      const size_t gi = ((size_t)b * 512 + m0 + h * 64 + m) * 1024 + n0 + c4 * 4;
      const f32x4 xr = *(const f32x4*)(x + gi);
      v += xr;
      *(f32x4*)(out + gi) = v;
    }
    __syncthreads();
  }
}

// ---------------------------------------------------------------------------
extern "C" void kernel_launch(void* const* d_in, const int* in_sizes, int n_in,
                              void* d_out, int out_size, void* d_ws, size_t ws_size,
                              hipStream_t stream) {
  const float* x     = (const float*)d_in[0];
  const float* Wq    = (const float*)d_in[1];
  const float* bq    = (const float*)d_in[2];
  const float* Wk    = (const float*)d_in[3];
  const float* bk    = (const float*)d_in[4];
  const float* Wv    = (const float*)d_in[5];
  const float* bv    = (const float*)d_in[6];
  const float* Wo    = (const float*)d_in[7];
  const float* bo    = (const float*)d_in[8];
  const float* gamma = (const float*)d_in[9];
  float* out = (float*)d_out;

  char* wsp = (char*)d_ws;
  ushort_t* xbfT   = (ushort_t*)wsp;  wsp += (size_t)16 * 1024 * 512 * 2;  // 16 MB
  ushort_t* Wqk_bf = (ushort_t*)wsp;  wsp += (size_t)128 * 512 * 2;
  ushort_t* Wv_bf  = (ushort_t*)wsp;  wsp += (size_t)512 * 512 * 2;
  ushort_t* Wo_bf  = (ushort_t*)wsp;  wsp += (size_t)512 * 512 * 2;
  ushort_t* qkt    = (ushort_t*)wsp;  wsp += (size_t)16 * 1024 * 128 * 2;  // 4 MB
  ushort_t* vt2    = (ushort_t*)wsp;  wsp += (size_t)16 * 512 * 1024 * 2;  // 16 MB
  ushort_t* o1     = xbfT;  // xbfT dead after k1; reuse for o1

  prep_x    <<<dim3(16, 9, 16), 256, 0, stream>>>(x, Wq, Wk, Wv, Wo,
                                                  xbfT, Wqk_bf, Wv_bf, Wo_bf);
  k1_fused  <<<768, 256, 0, stream>>>(xbfT, Wqk_bf, Wv_bf, bq, bk, bv, qkt, vt2);
  flash_attn<<<dim3(1024), 256, 0, stream>>>(qkt, vt2, o1);
  k4_proj   <<<dim3(8, 4, 16), 256, 0, stream>>>(Wo_bf, o1, bo, gamma, x, out);
}

// Round 4
// 178.992 us; speedup vs baseline: 1.0929x; 1.0553x over previous
//
#include <hip/hip_runtime.h>
#include <cstddef>

// QSelfAttention MI355X round 12: r11 resubmit (infra failure, no counters).
// r11 audit found no deadlock; defensive change: gemm_core per-step sync is
// plain __syncthreads() (same semantics as vmcnt(0)+s_barrier here — the
// pipeline's win is issuing the stage BEFORE compute, the step drains the
// prefetch regardless). Flash keeps r10's counted-wait structure (verified).
// Round intent unchanged:
//   gemm_core: 2-phase dbuf pipeline (stage k+1 before compute k).
//   k1/k4: 1-D grids + bijective XCD swizzle, batch-contiguous (each XCD
//     owns 2 whole batches; ~2.5MB L2-fit; r9 proved FETCH 43->10MB).
//   prep: f32x4 loads (16B/lane), LDS stride 66, 8B packed stores.

typedef unsigned short ushort_t;
typedef __attribute__((ext_vector_type(8))) short bf16x8;
typedef __attribute__((ext_vector_type(4))) float f32x4;
typedef __attribute__((ext_vector_type(2))) float f32x2;
typedef __attribute__((ext_vector_type(2))) unsigned u32x2;

#define QSCALE 0.18033688011112042f  // 0.125 * log2(e)

// truncating f32->bf16: 1 VALU op (intermediates only; tolerance ~2^-8 ok)
__device__ __forceinline__ ushort_t f2bf_t(float f) {
  return (ushort_t)(__float_as_uint(f) >> 16);
}
// pack 2 f32 -> 2 bf16 in one dword: single v_perm_b32
__device__ __forceinline__ unsigned pk2bf(float lo, float hi) {
  return __builtin_amdgcn_perm(__float_as_uint(hi), __float_as_uint(lo),
                               0x07060302u);
}

__device__ __forceinline__ void gload16(const ushort_t* g, ushort_t* l) {
  __builtin_amdgcn_global_load_lds(
      (const __attribute__((address_space(1))) void*)g,
      (__attribute__((address_space(3))) void*)l, 16, 0, 0);
}

// ---------------------------------------------------------------------------
// Core NT GEMM: D[M][N] = A[M][K] * B[N][K]^T, bf16 in, fp32 acc.
// TM in {64,128}, TN=128, BK=64, 256 threads (4 waves, 2x2 wave grid).
// 2-phase double-buffered pipeline: stage k+1 issued BEFORE computing k;
// one __syncthreads() per k-step (prefetch latency hidden under MFMA).
// As: 2 x TM*64 ush buffers at As; Bs: 2 x 128*64 ush buffers at Bs.
template <int TM>
__device__ __forceinline__ void gemm_core(
    const ushort_t* __restrict__ A, int lda,
    const ushort_t* __restrict__ B, int ldb,
    int K, int m0, int n0,
    ushort_t* As, ushort_t* Bs, f32x4 (*acc)[4])
{
  constexpr int MT  = TM / 32;
  constexpr int WTM = TM / 2;
  const int t = threadIdx.x;
  const int lane = t & 63, quad = lane >> 4, l15 = lane & 15;
  const int w = t >> 6, wm = w >> 1, wn = w & 1;
  const int rr = (lane >> 3) & 7;
  const int gg = (lane & 7) ^ rr;

  // stage k-step k0 into buffer pbuf
  auto stage = [&](int k0, int pbuf) {
    ushort_t* Ad = As + pbuf * (TM * 64);
    ushort_t* Bd = Bs + pbuf * (128 * 64);
    #pragma unroll
    for (int i = 0; i < TM / 32; ++i) {
      const int mrow = w * (TM / 4) + i * 8;
      gload16(A + (size_t)(m0 + mrow + rr) * lda + k0 + gg * 8, Ad + mrow * 64);
    }
    #pragma unroll
    for (int i = 0; i < 4; ++i) {
      const int mrow = w * 32 + i * 8;
      gload16(B + (size_t)(n0 + mrow + rr) * ldb + k0 + gg * 8, Bd + mrow * 64);
    }
  };

  stage(0, 0);

  #pragma unroll
  for (int i = 0; i < MT; ++i)
    #pragma unroll
    for (int j = 0; j < 4; ++j) acc[i][j] = (f32x4){0.f, 0.f, 0.f, 0.f};

  __syncthreads();  // chunk0 staged

  int pb = 0;
  for (int k0 = 0; k0 < K; k0 += 64) {
    if (k0 + 64 < K) stage(k0 + 64, pb ^ 1);  // in flight across compute
    const ushort_t* Ac = As + pb * (TM * 64);
    const ushort_t* Bc = Bs + pb * (128 * 64);
    #pragma unroll
    for (int kk = 0; kk < 2; ++kk) {
      const int gq = kk * 4 + quad;
      const int sg = (gq ^ (l15 & 7)) * 8;
      bf16x8 af[MT], bfr[4];
      #pragma unroll
      for (int i = 0; i < MT; ++i)
        af[i] = *(const bf16x8*)(Ac + (wm * WTM + i * 16 + l15) * 64 + sg);
      #pragma unroll
      for (int j = 0; j < 4; ++j)
        bfr[j] = *(const bf16x8*)(Bc + (wn * 64 + j * 16 + l15) * 64 + sg);
      #pragma unroll
      for (int i = 0; i < MT; ++i)
        #pragma unroll
        for (int j = 0; j < 4; ++j)
          acc[i][j] = __builtin_amdgcn_mfma_f32_16x16x32_bf16(
              af[i], bfr[j], acc[i][j], 0, 0, 0);
    }
    // prefetch (k0+64) drained + all waves' reads of buf pb done
    __syncthreads();
    pb ^= 1;
  }
}

template <int TM, class F>
__device__ __forceinline__ void store_bf16(
    ushort_t* lds, ushort_t* __restrict__ out, int ldo, int m0, int n0,
    f32x4 (*acc)[4], F f)
{
  constexpr int MT = TM / 32, WTM = TM / 2, SI = TM / 16;
  const int t = threadIdx.x;
  const int lane = t & 63, quad = lane >> 4, l15 = lane & 15;
  const int w = t >> 6, wm = w >> 1, wn = w & 1;
  #pragma unroll
  for (int i = 0; i < MT; ++i)
    #pragma unroll
    for (int j = 0; j < 4; ++j)
      #pragma unroll
      for (int r = 0; r < 4; ++r) {
        const int rl = wm * WTM + i * 16 + quad * 4 + r;
        const int cl = wn * 64 + j * 16 + l15;
        lds[rl * 136 + cl] = f2bf_t(f(i, j, r, rl, cl, acc[i][j][r]));
      }
  __syncthreads();
  #pragma unroll
  for (int i = 0; i < SI; ++i) {
    const int s = i * 256 + t, m = s >> 4, g = s & 15;
    const uint4 v = *(const uint4*)(lds + m * 136 + g * 8);
    *(uint4*)(out + (size_t)(m0 + m) * ldo + n0 + g * 8) = v;
  }
}

// ---------------------------------------------------------------------------
// prep: x[b][c][n] fp32 -> xbfT[b][n][c] bf16 (64x64 tiles, blockIdx.y<8)
//       + all weight fp32->bf16 conversions (blockIdx.y==8)
// Vectorized: f32x4 global loads (16B/lane), LDS stride 66, u32x2 stores.
__global__ __launch_bounds__(256) void prep_x(
    const float* __restrict__ x,
    const float* __restrict__ Wq, const float* __restrict__ Wk,
    const float* __restrict__ Wv, const float* __restrict__ Wo,
    ushort_t* __restrict__ xbfT, ushort_t* __restrict__ Wqk,
    ushort_t* __restrict__ Wvb, ushort_t* __restrict__ Wob)
{
  __shared__ float T[64 * 66];
  const int t = threadIdx.x;
  if (blockIdx.y == 8) {
    const int id = blockIdx.z * 16 + blockIdx.x;
    #pragma unroll
    for (int p = 0; p < 5; ++p) {
      const int s = p * 256 + t;
      if (s < 1152) {
        const int u = id * 1152 + s;
        const int e = u * 2;
        float f0, f1;
        if (e < 32768)       { f0 = Wq[e];         f1 = Wq[e + 1]; }
        else if (e < 65536)  { f0 = Wk[e - 32768]; f1 = Wk[e - 32767]; }
        else if (e < 327680) { f0 = Wv[e - 65536]; f1 = Wv[e - 65535]; }
        else                 { f0 = Wo[e - 327680]; f1 = Wo[e - 327679]; }
        const unsigned pk = pk2bf(f0, f1);
        if (e < 65536)       *((unsigned*)Wqk + u) = pk;
        else if (e < 327680) *((unsigned*)Wvb + (u - 32768)) = pk;
        else                 *((unsigned*)Wob + (u - 163840)) = pk;
      }
    }
    return;
  }
  const int b = blockIdx.z, c0 = blockIdx.y * 64, n0 = blockIdx.x * 64;
  const float* xb = x + ((size_t)b * 512 + c0) * 1024 + n0;
  // load: 16B/lane, 4 passes; T[ci][nj] = x[c0+ci][n0+nj]
  const int njf = t & 15, ci0 = t >> 4;
  #pragma unroll
  for (int p = 0; p < 4; ++p) {
    const int ci = p * 16 + ci0;
    const f32x4 v = *(const f32x4*)(xb + (size_t)ci * 1024 + njf * 4);
    float* d = &T[ci * 66 + njf * 4];
    *(f32x2*)(d)     = (f32x2){v[0], v[1]};
    *(f32x2*)(d + 2) = (f32x2){v[2], v[3]};
  }
  __syncthreads();
  // transpose out: thread -> 4 c-values of one n-row; 8B store
  const int c4 = (t & 15) * 4, nr0 = t >> 4;
  #pragma unroll
  for (int p = 0; p < 4; ++p) {
    const int nr = p * 16 + nr0;
    const float a0 = T[(c4 + 0) * 66 + nr];
    const float a1 = T[(c4 + 1) * 66 + nr];
    const float a2 = T[(c4 + 2) * 66 + nr];
    const float a3 = T[(c4 + 3) * 66 + nr];
    const u32x2 pkv = {pk2bf(a0, a1), pk2bf(a2, a3)};
    *(u32x2*)&xbfT[((size_t)b * 1024 + n0 + nr) * 512 + c0 + c4] = pkv;
  }
}

// ---------------------------------------------------------------------------
// k1 fused, batch-contiguous work ids + bijective XCD swizzle (768 = 8*96):
//   wid = (lin&7)*96 + lin>>3 ; b = wid/48, r = wid%48
//   r<32  -> V projection (vt2[b][c][n], TM=128), m0=(r>>3)*128, n0=(r&7)*128
//   r>=32 -> QK projection (qkt[b][n][128], TM=64), m0=(r-32)*64
__global__ __launch_bounds__(256) void k1_fused(
    const ushort_t* __restrict__ xbfT, const ushort_t* __restrict__ Wqk,
    const ushort_t* __restrict__ Wvb,
    const float* __restrict__ bq, const float* __restrict__ bk,
    const float* __restrict__ bv,
    ushort_t* __restrict__ qkt, ushort_t* __restrict__ vt2)
{
  __shared__ __align__(16) ushort_t lds[32768];  // 64KB: dbuf staging
  const unsigned lin = blockIdx.x;
  const unsigned wid = (lin & 7) * 96 + (lin >> 3);
  const int b = wid / 48, r = wid % 48;
  const int t = threadIdx.x, lane = t & 63, quad = lane >> 4, l15 = lane & 15;
  const int w = t >> 6, wm = w >> 1, wn = w & 1;
  if (r < 32) {
    const int m0 = (r >> 3) * 128, n0 = (r & 7) * 128;
    f32x4 acc[4][4];
    gemm_core<128>(Wvb, 512, xbfT + (size_t)b * 524288, 512, 512, m0, n0,
                   lds, lds + 16384, acc);
    float br[4][4];
    #pragma unroll
    for (int i = 0; i < 4; ++i)
      #pragma unroll
      for (int rr2 = 0; rr2 < 4; ++rr2)
        br[i][rr2] = bv[m0 + wm * 64 + i * 16 + quad * 4 + rr2];
    store_bf16<128>(lds, vt2 + (size_t)b * 524288, 1024, m0, n0, acc,
        [&](int i, int, int rr2, int, int, float v) { return v + br[i][rr2]; });
  } else {
    const int m0 = (r - 32) * 64;
    f32x4 acc[2][4];
    gemm_core<64>(xbfT + (size_t)b * 524288, 512, Wqk, 512, 512, m0, 0,
                  lds, lds + 8192, acc);
    float bc[4], qs[4];
    #pragma unroll
    for (int j = 0; j < 4; ++j) {
      const int col = wn * 64 + j * 16 + l15;
      bc[j] = (col < 64) ? bq[col] : bk[col - 64];
      qs[j] = (col < 64) ? QSCALE : 1.0f;
    }
    store_bf16<64>(lds, qkt + (size_t)b * 131072, 128, m0, 0, acc,
        [&](int, int j, int, int, int, float v) { return (v + bc[j]) * qs[j]; });
  }
}

// ---------------------------------------------------------------------------
// flash: byte-identical structure to r10 (2-phase dbuf, 2 barriers/chunk).
__global__ __launch_bounds__(256) void flash_attn(
    const ushort_t* __restrict__ qkt, const ushort_t* __restrict__ vt2,
    ushort_t* __restrict__ o1)
{
  __shared__ __align__(16) ushort_t buf[33792];
  __shared__ float lsum[64][2];
  ushort_t* Ks0 = buf;            // 2 x 4096 ush
  ushort_t* Vs0 = buf + 8192;     // 2 x 8192 ush
  ushort_t* Ps0 = buf + 24576;    // 2 x 4608 ush (stride 72); Q-stage uses Ps0

  const int t = threadIdx.x;
  const int lane = t & 63, quad = lane >> 4, l15 = lane & 15;
  const int w = t >> 6, wm = w >> 1, wn = w & 1;
  const int rr = (lane >> 3) & 7, gg = (lane & 7) ^ rr;

  // XCD-aware bijective swizzle: hw linear id -> work id
  const unsigned lin = blockIdx.x;
  const unsigned wid = (lin & 7) * 128 + (lin >> 3);
  const int b  = wid >> 6;
  const int m0 = ((wid >> 2) & 15) * 64;
  const int c0 = (wid & 3) * 128;

  const ushort_t* qb = qkt + (size_t)b * 131072;   // [n][128]: q 0..63, k 64..127
  const ushort_t* vb = vt2 + (size_t)b * 524288;   // [c][1024]

  // ---- prologue: stage Q (64x64) into Ps0 region
  #pragma unroll
  for (int i = 0; i < 2; ++i) {
    const int mrow = w * 16 + i * 8;
    gload16(qb + (size_t)(m0 + mrow + rr) * 128 + gg * 8, Ps0 + mrow * 64);
  }
  asm volatile("s_waitcnt vmcnt(0)" ::: "memory");
  __builtin_amdgcn_s_barrier();

  // pull Q fragments to registers
  bf16x8 af_q[2][2];
  #pragma unroll
  for (int kk = 0; kk < 2; ++kk) {
    const int sg = ((kk * 4 + quad) ^ (l15 & 7)) * 8;
    #pragma unroll
    for (int i = 0; i < 2; ++i)
      af_q[i][kk] = *(const bf16x8*)(Ps0 + (wm * 32 + i * 16 + l15) * 64 + sg);
  }

  // running global source pointers (advance per chunk)
  const ushort_t* kp = qb + (size_t)(w * 16 + rr) * 128 + 64 + gg * 8;
  const ushort_t* vp = vb + (size_t)(c0 + w * 32 + rr) * 1024 + gg * 8;

  // stage chunk 0 into buf0
  #pragma unroll
  for (int i = 0; i < 2; ++i)
    gload16(kp + i * 1024, Ks0 + (w * 16 + i * 8) * 64);
  #pragma unroll
  for (int i = 0; i < 4; ++i)
    gload16(vp + i * 8192, Vs0 + (w * 32 + i * 8) * 64);
  asm volatile("s_waitcnt vmcnt(0) lgkmcnt(0)" ::: "memory");
  __builtin_amdgcn_s_barrier();

  f32x4 accO[2][4];
  #pragma unroll
  for (int i = 0; i < 2; ++i)
    #pragma unroll
    for (int j = 0; j < 4; ++j) accO[i][j] = (f32x4){0.f, 0.f, 0.f, 0.f};
  float rsum[2][4] = {{0.f, 0.f, 0.f, 0.f}, {0.f, 0.f, 0.f, 0.f}};

  const int psw_off = (wm * 32 + quad * 4) * 72 + wn * 32 + l15;
  const int sg0 = (quad ^ (l15 & 7)) * 8;
  const int sg1 = ((4 + quad) ^ (l15 & 7)) * 8;

  const ushort_t* kpn = kp + 8192;  // next-chunk K source
  const ushort_t* vpn = vp + 64;    // next-chunk V source
  int p = 0;

  #pragma unroll 1
  for (int mc = 0; mc < 1024; mc += 64) {
    ushort_t* Ksd = p ? Ks0 + 4096 : Ks0;
    ushort_t* Vsd = p ? Vs0 + 8192 : Vs0;
    ushort_t* Psd = p ? Ps0 + 4608 : Ps0;
    ushort_t* Ksn = p ? Ks0 : Ks0 + 4096;
    ushort_t* Vsn = p ? Vs0 : Vs0 + 8192;

    // 1) prefetch next chunk into the other buffer (stays in flight)
    if (mc < 960) {
      #pragma unroll
      for (int i = 0; i < 2; ++i)
        gload16(kpn + i * 1024, Ksn + (w * 16 + i * 8) * 64);
      #pragma unroll
      for (int i = 0; i < 4; ++i)
        gload16(vpn + i * 8192, Vsn + (w * 32 + i * 8) * 64);
    }

    // 2) S-phase: rows wm*32+{0,16}, keys wn*32+{0,16}, K=64 (Q pre-scaled)
    f32x4 accS[2][2];
    #pragma unroll
    for (int i = 0; i < 2; ++i)
      #pragma unroll
      for (int j = 0; j < 2; ++j) accS[i][j] = (f32x4){0.f, 0.f, 0.f, 0.f};
    #pragma unroll
    for (int kk = 0; kk < 2; ++kk) {
      const int sg = kk ? sg1 : sg0;
      bf16x8 bk_[2];
      #pragma unroll
      for (int j = 0; j < 2; ++j)
        bk_[j] = *(const bf16x8*)(Ksd + (wn * 32 + j * 16 + l15) * 64 + sg);
      #pragma unroll
      for (int i = 0; i < 2; ++i)
        #pragma unroll
        for (int j = 0; j < 2; ++j)
          accS[i][j] = __builtin_amdgcn_mfma_f32_16x16x32_bf16(
              af_q[i][kk], bk_[j], accS[i][j], 0, 0, 0);
    }

    // 3) exp2 -> rsum partials -> Ps[p] (trunc bf16)
    ushort_t* psw = Psd + psw_off;
    #pragma unroll
    for (int i = 0; i < 2; ++i)
      #pragma unroll
      for (int j = 0; j < 2; ++j)
        #pragma unroll
        for (int r2 = 0; r2 < 4; ++r2) {
          const float e = __builtin_amdgcn_exp2f(accS[i][j][r2]);
          rsum[i][r2] += e;
          psw[(i * 16 + r2) * 72 + j * 16] = f2bf_t(e);
        }

    // 4) own ds ops done -> barrier: Ps[p] visible (prefetch NOT drained)
    asm volatile("s_waitcnt lgkmcnt(0)" ::: "memory");
    __builtin_amdgcn_s_barrier();

    // 5) PV-phase: O[64][128] += Ps[p][64][64] . Vs[p][128][64]^T
    #pragma unroll
    for (int kk = 0; kk < 2; ++kk) {
      const int gq = kk * 4 + quad;
      const int sgv = kk ? sg1 : sg0;
      bf16x8 ap[2], bv_[4];
      #pragma unroll
      for (int i = 0; i < 2; ++i)
        ap[i] = *(const bf16x8*)(Psd + (wm * 32 + i * 16 + l15) * 72 + gq * 8);
      #pragma unroll
      for (int j = 0; j < 4; ++j)
        bv_[j] = *(const bf16x8*)(Vsd + (wn * 64 + j * 16 + l15) * 64 + sgv);
      #pragma unroll
      for (int i = 0; i < 2; ++i)
        #pragma unroll
        for (int j = 0; j < 4; ++j)
          accO[i][j] = __builtin_amdgcn_mfma_f32_16x16x32_bf16(
              ap[i], bv_[j], accO[i][j], 0, 0, 0);
    }

    // 6) next chunk's DMA landed; all waves synced -> buffers swappable
    asm volatile("s_waitcnt vmcnt(0)" ::: "memory");
    __builtin_amdgcn_s_barrier();

    kpn += 8192;
    vpn += 64;
    p ^= 1;
  }

  // finish row sums: reduce over the 16 key-lanes, combine the two wn waves
  #pragma unroll
  for (int i = 0; i < 2; ++i)
    #pragma unroll
    for (int r2 = 0; r2 < 4; ++r2) {
      float s = rsum[i][r2];
      #pragma unroll
      for (int d = 1; d < 16; d <<= 1) s += __shfl_xor(s, d, 16);
      if (l15 == 0) lsum[wm * 32 + i * 16 + quad * 4 + r2][wn] = s;
    }
  __syncthreads();  // also: last PV's LDS reads done before fl_b overwrite

  ushort_t* fl_b = buf;  // [64][136] = 8704 ush, fits (Ks/Vs/Ps dead)
  #pragma unroll
  for (int i = 0; i < 2; ++i)
    #pragma unroll
    for (int r2 = 0; r2 < 4; ++r2) {
      const int row = wm * 32 + i * 16 + quad * 4 + r2;
      const float inv = 1.0f / (lsum[row][0] + lsum[row][1]);
      #pragma unroll
      for (int j = 0; j < 4; ++j)
        fl_b[row * 136 + wn * 64 + j * 16 + l15] = f2bf_t(accO[i][j][r2] * inv);
    }
  __syncthreads();
  #pragma unroll
  for (int pp = 0; pp < 4; ++pp) {
    const int s = pp * 256 + t, m = s >> 4, g = s & 15;
    const uint4 v = *(const uint4*)(fl_b + m * 136 + g * 8);
    *(uint4*)(o1 + ((size_t)b * 1024 + m0 + m) * 512 + c0 + g * 8) = v;
  }
}

// ---------------------------------------------------------------------------
// K4: out[b][c][n] = g*(Wo @ o1^T + bo) + x.  M=c(512) N=n(1024) K=v(512)
// 1-D grid 512 = 8*64, bijective XCD swizzle: XCD k owns batches {2k,2k+1}.
// Residual path kept exact fp32.
__global__ __launch_bounds__(256) void k4_proj(
    const ushort_t* __restrict__ Wob, const ushort_t* __restrict__ o1,
    const float* __restrict__ bo, const float* __restrict__ gamma,
    const float* __restrict__ x, float* __restrict__ out)
{
  __shared__ __align__(16) ushort_t lds[32768];  // 64KB: dbuf staging
  const unsigned lin = blockIdx.x;
  const unsigned wid = (lin & 7) * 64 + (lin >> 3);
  const int b = wid >> 5, rem = wid & 31;
  const int m0 = (rem >> 3) * 128, n0 = (rem & 7) * 128;
  f32x4 acc[4][4];
  gemm_core<128>(Wob, 512, o1 + (size_t)b * 524288, 512, 512, m0, n0,
                 lds, lds + 16384, acc);
  const int t = threadIdx.x, lane = t & 63, quad = lane >> 4, l15 = lane & 15;
  const int w = t >> 6, wm = w >> 1, wn = w & 1;
  const float g = gamma[0];
  float br[4][4];
  #pragma unroll
  for (int i = 0; i < 4; ++i)
    #pragma unroll
    for (int r2 = 0; r2 < 4; ++r2)
      br[i][r2] = bo[m0 + wm * 64 + i * 16 + quad * 4 + r2];
  float* fl = (float*)lds;  // 64 rows x 132 f stride
  #pragma unroll
  for (int h = 0; h < 2; ++h) {
    if (wm == h) {
      #pragma unroll
      for (int i = 0; i < 4; ++i)
        #pragma unroll
        for (int j = 0; j < 4; ++j)
          #pragma unroll
          for (int r2 = 0; r2 < 4; ++r2)
            fl[(i * 16 + quad * 4 + r2) * 132 + wn * 64 + j * 16 + l15] =
                g * (acc[i][j][r2] + br[i][r2]);
    }
    __syncthreads();
    #pragma unroll
    for (int i2 = 0; i2 < 8; ++i2) {
      const int s = i2 * 256 + t, m = s >> 5, c4 = s & 31;
      f32x4 v = *(const f32x4*)(fl + m * 132 + c4 * 4);
      const size_t gi = ((size_t)b * 512 + m0 + h * 64 + m) * 1024 + n0 + c4 * 4;
      const f32x4 xr = *(const f32x4*)(x + gi);
      v += xr;
      *(f32x4*)(out + gi) = v;
    }
    __syncthreads();
  }
}

// ---------------------------------------------------------------------------
extern "C" void kernel_launch(void* const* d_in, const int* in_sizes, int n_in,
                              void* d_out, int out_size, void* d_ws, size_t ws_size,
                              hipStream_t stream) {
  const float* x     = (const float*)d_in[0];
  const float* Wq    = (const float*)d_in[1];
  const float* bq    = (const float*)d_in[2];
  const float* Wk    = (const float*)d_in[3];
  const float* bk    = (const float*)d_in[4];
  const float* Wv    = (const float*)d_in[5];
  const float* bv    = (const float*)d_in[6];
  const float* Wo    = (const float*)d_in[7];
  const float* bo    = (const float*)d_in[8];
  const float* gamma = (const float*)d_in[9];
  float* out = (float*)d_out;

  char* wsp = (char*)d_ws;
  ushort_t* xbfT   = (ushort_t*)wsp;  wsp += (size_t)16 * 1024 * 512 * 2;  // 16 MB
  ushort_t* Wqk_bf = (ushort_t*)wsp;  wsp += (size_t)128 * 512 * 2;
  ushort_t* Wv_bf  = (ushort_t*)wsp;  wsp += (size_t)512 * 512 * 2;
  ushort_t* Wo_bf  = (ushort_t*)wsp;  wsp += (size_t)512 * 512 * 2;
  ushort_t* qkt    = (ushort_t*)wsp;  wsp += (size_t)16 * 1024 * 128 * 2;  // 4 MB
  ushort_t* vt2    = (ushort_t*)wsp;  wsp += (size_t)16 * 512 * 1024 * 2;  // 16 MB
  ushort_t* o1     = xbfT;  // xbfT dead after k1; reuse for o1

  prep_x    <<<dim3(16, 9, 16), 256, 0, stream>>>(x, Wq, Wk, Wv, Wo,
                                                  xbfT, Wqk_bf, Wv_bf, Wo_bf);
  k1_fused  <<<768, 256, 0, stream>>>(xbfT, Wqk_bf, Wv_bf, bq, bk, bv, qkt, vt2);
  flash_attn<<<dim3(1024), 256, 0, stream>>>(qkt, vt2, o1);
  k4_proj   <<<512, 256, 0, stream>>>(Wo_bf, o1, bo, gamma, x, out);
}